// Round 15
// baseline (103.699 us; speedup 1.0000x reference)
//
#include <hip/hip_runtime.h>
#include <hip/hip_bf16.h>

typedef __bf16 bf16;
typedef __attribute__((ext_vector_type(2))) __bf16 bf16x2;
typedef __attribute__((ext_vector_type(4))) __bf16 bf16x4;
typedef __attribute__((ext_vector_type(8))) __bf16 bf16x8;
typedef __attribute__((ext_vector_type(4))) float f32x4;

#define NB 4
#define NS 1024
#define NE 1024
#define NH 16
#define ND 64
#define NROT 32
#define NM (NB*NS)   // 4096 rows

// ---- async global->LDS, 16B per lane, wave-uniform LDS base ----
__device__ __forceinline__ void gload_lds16(const bf16* g, void* l) {
  __builtin_amdgcn_global_load_lds(
      (const __attribute__((address_space(1))) unsigned int*)g,
      (__attribute__((address_space(3))) unsigned int*)l,
      16, 0, 0);
}

// ---- fused prep: weight cvt (y<4), hidden cvt (y<8), rope tables (y==8) ----
struct PrepArgs {
  const float* w0; const float* w1; const float* w2; const float* w3;
  bf16* b0; bf16* b1; bf16* b2; bf16* b3;
  const float* hs; bf16* hb;
  const float* rot; float* ct; float* st;
};
__global__ void k_prep(PrepArgs a) {
  const int y = blockIdx.y;
  const int i = blockIdx.x * 256 + threadIdx.x;
  if (y < 4) {
    const float* s = (y == 0) ? a.w0 : (y == 1) ? a.w1 : (y == 2) ? a.w2 : a.w3;
    bf16* d = (y == 0) ? a.b0 : (y == 1) ? a.b1 : (y == 2) ? a.b2 : a.b3;
    float4 v = reinterpret_cast<const float4*>(s)[i];
    bf16x4 o = { (bf16)v.x, (bf16)v.y, (bf16)v.z, (bf16)v.w };
    *reinterpret_cast<bf16x4*>(d + (size_t)i * 4) = o;
  } else if (y < 8) {
    size_t off = (size_t)(y - 4) * (NM * NE / 16);   // quarter of hidden, in float4s
    float4 v = reinterpret_cast<const float4*>(a.hs)[off + i];
    bf16x4 o = { (bf16)v.x, (bf16)v.y, (bf16)v.z, (bf16)v.w };
    *reinterpret_cast<bf16x4*>(a.hb + (off + i) * 4) = o;
  } else {
    if (i < NS * NROT) {
      float v = a.rot[i];
      a.ct[i] = cosf(v);
      a.st[i] = sinf(v);
    }
  }
}

// =====================================================================
// 256x256-tile GEMM core, BK=32, TRIPLE-buffered, one barrier per K-tile.
// 512 threads / 8 waves (2M x 4N), wave C = 128x64.
// Per tile t: vmcnt(4)+barrier (publish t; t+1's 4 loads stay in flight)
//   -> stage tile t+2 (buffer free: all waves past barrier => t-1 reads done)
//   -> 12 ds_read_b128 + 32 MFMA (setprio).
// Flight per tile ~ 2 compute-tiles. LDS 3x(16K+16K)=96KB.
// LDS pack: 2 rows x 32 bf16 per 128B line, 16B-slot XOR by line (2-way=free).
// acc flat [32]: normal idx = i*4+j; SWAP idx = j*8+i.
// =====================================================================
template<bool SWAP>
__device__ __forceinline__ void gemm_core256(
    const bf16* __restrict__ A, const bf16* __restrict__ W,
    bf16* lA, bf16* lB, int m0, int n0, f32x4 (&acc)[32])
{
  const int tid = threadIdx.x;
  const int wave = tid >> 6, lane = tid & 63;
  const int wm = wave >> 2, wn = wave & 3;      // 2 m-halves x 4 n-quarters
  const int fr = lane & 15, kg = lane >> 4;

  // staging source mapping (per-lane, invariant): chunk=1KB=8 lines=16 rows
  const int sline = lane >> 3;                 // line within chunk (0..7)
  const int lsl   = (lane & 7) ^ sline;        // logical slot (XOR swizzle)
  const int srow  = 2 * sline + (lsl >> 2);    // row within 16-row chunk
  const int skcol = (lsl & 3) * 8;             // k column (bf16 elems, 0..24)

  auto stage = [&](int t) {
    const int kt = t * 32;
    const int c = t % 3;
#pragma unroll
    for (int i = 0; i < 2; ++i) {
      int chunk = i * 8 + wave;                // 16 chunks per operand / 8 waves
      gload_lds16(A + (size_t)(m0 + chunk * 16 + srow) * NE + kt + skcol,
                  (char*)lA + c * 16384 + chunk * 1024);
      gload_lds16(W + (size_t)(n0 + chunk * 16 + srow) * NE + kt + skcol,
                  (char*)lB + c * 16384 + chunk * 1024);
    }
  };

  // frag read byte-offset for row ra, k-group kg (within 16KB tile region)
  auto foff = [&](int ra) {
    return (ra >> 1) * 128 + (((((ra & 1) << 2) + kg) ^ ((ra >> 1) & 7)) << 4);
  };

  constexpr int NT = NE / 32;   // 32
  stage(0);
  stage(1);

  for (int t = 0; t < NT; ++t) {
    const int c = t % 3;
    // publish tile t: own loads of t are the oldest; allow t+1's 4 to fly.
    if (t + 1 < NT)
      asm volatile("s_waitcnt vmcnt(4)\n\ts_barrier" ::: "memory");
    else
      asm volatile("s_waitcnt vmcnt(0)\n\ts_barrier" ::: "memory");
    // stage tile t+2 into buffer (t+2)%3 — its last readers (tile t-1)
    // finished before this barrier (their ds-reads drained pre-MFMA).
    if (t + 2 < NT) stage(t + 2);

    const char* cA = (const char*)lA + c * 16384;
    const char* cB = (const char*)lB + c * 16384;
    bf16x8 af[8], bfr[4];
#pragma unroll
    for (int i = 0; i < 8; ++i)
      af[i] = *reinterpret_cast<const bf16x8*>(cA + foff(wm * 128 + i * 16 + fr));
#pragma unroll
    for (int j = 0; j < 4; ++j)
      bfr[j] = *reinterpret_cast<const bf16x8*>(cB + foff(wn * 64 + j * 16 + fr));

    __builtin_amdgcn_s_setprio(1);
#pragma unroll
    for (int i = 0; i < 8; ++i)
#pragma unroll
      for (int j = 0; j < 4; ++j) {
        if constexpr (SWAP)
          acc[j * 8 + i] = __builtin_amdgcn_mfma_f32_16x16x32_bf16(
              bfr[j], af[i], acc[j * 8 + i], 0, 0, 0);
        else
          acc[i * 4 + j] = __builtin_amdgcn_mfma_f32_16x16x32_bf16(
              af[i], bfr[j], acc[i * 4 + j], 0, 0, 0);
      }
    __builtin_amdgcn_s_setprio(0);
  }
}

// ---- fused projections + rope, 256^2 tiles: z=0 Q, z=1 K, z=2 V-transposed ----
__global__ __launch_bounds__(512) void k_proj(
    const bf16* __restrict__ A, const bf16* __restrict__ Wq, const bf16* __restrict__ Wk,
    const bf16* __restrict__ Wv, bf16* __restrict__ Oq, bf16* __restrict__ Ok,
    bf16* __restrict__ vt, const float* __restrict__ ct, const float* __restrict__ st)
{
  __shared__ bf16 lA[3 * 256 * 32];
  __shared__ bf16 lB[3 * 256 * 32];
  const int z = blockIdx.z;
  const int m0 = blockIdx.x * 256, n0 = blockIdx.y * 256;
  const int tid = threadIdx.x;
  const int wave = tid >> 6, lane = tid & 63;
  const int wm = wave >> 2, wn = wave & 3;
  const int fr = lane & 15, kg = lane >> 4;

  f32x4 acc[32] = {};

  if (z == 2) {
    gemm_core256<true>(A, Wv, lA, lB, m0, n0, acc);

    const int b = m0 >> 10;
    const int h = (n0 + wn * 64) >> 6;
    bf16* vtb = vt + ((size_t)(b * 16 + h)) * ND * NS;
#pragma unroll
    for (int i = 0; i < 8; ++i) {
      int sl = (m0 & (NS - 1)) + wm * 128 + i * 16 + fr;
#pragma unroll
      for (int r = 0; r < 4; ++r) {
        int dbase = kg * 4 + r;
        float x0 = acc[0 * 8 + i][r];
        float x1 = acc[1 * 8 + i][r];
        float c0 = ct[sl * NROT + dbase],      sn0 = st[sl * NROT + dbase];
        float c1 = ct[sl * NROT + 16 + dbase], sn1 = st[sl * NROT + 16 + dbase];
        float y0 = x0 * c0 - x1 * sn0;
        float y1 = x1 * c1 + x0 * sn1;
        vtb[(size_t)(dbase)      * NS + sl] = (bf16)y0;
        vtb[(size_t)(16 + dbase) * NS + sl] = (bf16)y1;
        vtb[(size_t)(32 + dbase) * NS + sl] = (bf16)acc[2 * 8 + i][r];
        vtb[(size_t)(48 + dbase) * NS + sl] = (bf16)acc[3 * 8 + i][r];
      }
    }
  } else {
    const bf16* W = (z == 0) ? Wq : Wk;
    bf16* Og = (z == 0) ? Oq : Ok;
    const float scale = (z == 0) ? 0.125f * 1.44269504f : 1.0f;

    gemm_core256<false>(A, W, lA, lB, m0, n0, acc);

#pragma unroll
    for (int i = 0; i < 8; ++i) {
      int rowbase = m0 + wm * 128 + i * 16 + kg * 4;
#pragma unroll
      for (int r = 0; r < 4; ++r) {
        int gm = rowbase + r;
        int s = gm & (NS - 1);
        float x0 = acc[i * 4 + 0][r] * scale;
        float x1 = acc[i * 4 + 1][r] * scale;
        float c0 = ct[s * NROT + fr],      sn0 = st[s * NROT + fr];
        float c1 = ct[s * NROT + 16 + fr], sn1 = st[s * NROT + 16 + fr];
        float y0 = x0 * c0 - x1 * sn0;
        float y1 = x1 * c1 + x0 * sn1;
        size_t rb = (size_t)gm * NE + n0 + wn * 64;
        Og[rb + 0 * 16 + fr] = (bf16)y0;
        Og[rb + 1 * 16 + fr] = (bf16)y1;
        Og[rb + 2 * 16 + fr] = (bf16)(acc[i * 4 + 2][r] * scale);
        Og[rb + 3 * 16 + fr] = (bf16)(acc[i * 4 + 3][r] * scale);
      }
    }
  }
}

// ---- output projection + bias: R6 simple single-buffered core ----
__global__ __launch_bounds__(256) void k_gemm_o(
    const bf16* __restrict__ A, const bf16* __restrict__ W, float* __restrict__ Og,
    const float* __restrict__ bias)
{
  __shared__ bf16 lA[64 * 64];
  __shared__ bf16 lB[128 * 64];
  const int m0 = blockIdx.x * 64, n0 = blockIdx.y * 128;
  const int tid = threadIdx.x;
  const int wave = tid >> 6, lane = tid & 63;
  const int wm = wave >> 1, wn = wave & 1;
  const int fr = lane & 15, kg = lane >> 4;
  const int lrow8 = lane >> 3, lslot = lane & 7;

  f32x4 acc[2][4] = {};

  for (int kt = 0; kt < NE; kt += 64) {
#pragma unroll
    for (int i = 0; i < 2; ++i) {
      int chunk = i * 4 + wave;
      int row = (chunk << 3) + lrow8;
      int slot = lslot ^ (row & 7);
      gload_lds16(A + (size_t)(m0 + row) * NE + kt + slot * 8, (char*)lA + chunk * 1024);
    }
#pragma unroll
    for (int i = 0; i < 4; ++i) {
      int chunk = i * 4 + wave;
      int row = (chunk << 3) + lrow8;
      int slot = lslot ^ (row & 7);
      gload_lds16(W + (size_t)(n0 + row) * NE + kt + slot * 8, (char*)lB + chunk * 1024);
    }
    __syncthreads();
#pragma unroll
    for (int kk = 0; kk < 2; ++kk) {
      bf16x8 af[2], bfr[4];
#pragma unroll
      for (int i = 0; i < 2; ++i) {
        int ra = wm * 32 + i * 16 + fr;
        af[i] = *reinterpret_cast<const bf16x8*>(lA + ra * 64 + (((kg + 4 * kk) ^ (ra & 7)) << 3));
      }
#pragma unroll
      for (int j = 0; j < 4; ++j) {
        int rb = wn * 64 + j * 16 + fr;
        bfr[j] = *reinterpret_cast<const bf16x8*>(lB + rb * 64 + (((kg + 4 * kk) ^ (rb & 7)) << 3));
      }
#pragma unroll
      for (int i = 0; i < 2; ++i)
#pragma unroll
        for (int j = 0; j < 4; ++j)
          acc[i][j] = __builtin_amdgcn_mfma_f32_16x16x32_bf16(af[i], bfr[j], acc[i][j], 0, 0, 0);
    }
    __syncthreads();
  }

#pragma unroll
  for (int i = 0; i < 2; ++i)
#pragma unroll
    for (int j = 0; j < 4; ++j) {
      int gc = n0 + wn * 64 + j * 16 + fr;
      float bv = bias[gc];
#pragma unroll
      for (int r = 0; r < 4; ++r) {
        int gm = m0 + wm * 32 + i * 16 + kg * 4 + r;
        Og[(size_t)gm * NE + gc] = acc[i][j][r] + bv;
      }
    }
}

// ---- causal flash attention (R12 version — proven) ----
__global__ __launch_bounds__(256) void k_attn(
    const bf16* __restrict__ Q, const bf16* __restrict__ K,
    const bf16* __restrict__ VT, bf16* __restrict__ O)
{
  __shared__ bf16 lK[2][64 * 64];
  __shared__ bf16 lVT[64 * 64];
  __shared__ bf16 lP[4][16 * 68];
  const int tid = threadIdx.x;
  const int wave = tid >> 6, lane = tid & 63;
  const int fr = lane & 15, kg = lane >> 4;

  const int qt = 15 - (blockIdx.y >> 3);          // descending: long blocks first
  const int bh = blockIdx.x | ((blockIdx.y & 7) << 3);
  const int b = bh >> 4, h = bh & 15;
  const int nt = qt + 1;
  const bf16* Qb  = Q + (size_t)b * NS * NE + h * 64;
  const bf16* Kb  = K + (size_t)b * NS * NE + h * 64;
  const bf16* VTb = VT + (size_t)bh * ND * NS;
  bf16* Ob = O + (size_t)b * NS * NE + h * 64;

  const int qrow0 = qt * 64 + wave * 16;

  bf16x8 qf[2];
#pragma unroll
  for (int kk = 0; kk < 2; ++kk)
    qf[kk] = *reinterpret_cast<const bf16x8*>(
        Qb + (size_t)(qrow0 + fr) * NE + kk * 32 + kg * 8);

  const int srow = lane >> 3;
  const int sslot = (lane & 7) ^ srow;
  const int r0 = wave * 8 + srow;
  const int r1 = (wave + 4) * 8 + srow;
  const bf16* kA0 = Kb + (size_t)r0 * NE + sslot * 8;
  const bf16* kA1 = Kb + (size_t)r1 * NE + sslot * 8;
  const bf16* vA0 = VTb + (size_t)r0 * NS + sslot * 8;
  const bf16* vA1 = VTb + (size_t)r1 * NS + sslot * 8;
  char* ldsKa[2] = { (char*)lK[0] + wave * 1024, (char*)lK[1] + wave * 1024 };
  char* ldsKb[2] = { (char*)lK[0] + (wave + 4) * 1024, (char*)lK[1] + (wave + 4) * 1024 };
  char* ldsVa  = (char*)lVT + wave * 1024;
  char* ldsVb  = (char*)lVT + (wave + 4) * 1024;

  float m_ = -3.0e38f, l_ = 0.f;
  f32x4 oacc[4] = {};

  gload_lds16(kA0, ldsKa[0]);
  gload_lds16(kA1, ldsKb[0]);
  __syncthreads();

  for (int t = 0; t < nt; ++t) {
    const int c = t & 1;
    gload_lds16(vA0 + t * 64, ldsVa);
    gload_lds16(vA1 + t * 64, ldsVb);
    if (t + 1 < nt) {
      gload_lds16(kA0 + (size_t)(t + 1) * 64 * NE, ldsKa[c ^ 1]);
      gload_lds16(kA1 + (size_t)(t + 1) * 64 * NE, ldsKb[c ^ 1]);
    }

    const bf16* lKc = lK[c];
    f32x4 sacc[4] = {};
    __builtin_amdgcn_s_setprio(1);
#pragma unroll
    for (int kk = 0; kk < 2; ++kk)
#pragma unroll
      for (int j = 0; j < 4; ++j) {
        int rc = j * 16 + fr;
        bf16x8 kf = *reinterpret_cast<const bf16x8*>(
            lKc + rc * 64 + (((kg + 4 * kk) ^ (rc & 7)) << 3));
        sacc[j] = __builtin_amdgcn_mfma_f32_16x16x32_bf16(kf, qf[kk], sacc[j], 0, 0, 0);
      }
    __builtin_amdgcn_s_setprio(0);

    if (t == qt) {
      const int ql = wave * 16 + fr;
#pragma unroll
      for (int j = 0; j < 4; ++j)
#pragma unroll
        for (int r = 0; r < 4; ++r)
          if (16 * j + 4 * kg + r > ql) sacc[j][r] = -3.0e38f;
    }

    float m4 = fmaxf(fmaxf(fmaxf(sacc[0][0], sacc[0][1]), fmaxf(sacc[0][2], sacc[0][3])),
                     fmaxf(fmaxf(sacc[1][0], sacc[1][1]), fmaxf(sacc[1][2], sacc[1][3])));
    m4 = fmaxf(m4, fmaxf(fmaxf(fmaxf(sacc[2][0], sacc[2][1]), fmaxf(sacc[2][2], sacc[2][3])),
                         fmaxf(fmaxf(sacc[3][0], sacc[3][1]), fmaxf(sacc[3][2], sacc[3][3]))));
    m4 = fmaxf(m4, __shfl_xor(m4, 16));
    m4 = fmaxf(m4, __shfl_xor(m4, 32));

    if (!__all(m4 - m_ <= 8.0f)) {
      float nm = fmaxf(m_, m4);
      float corr = exp2f(m_ - nm);
      m_ = nm;
      l_ *= corr;
#pragma unroll
      for (int r = 0; r < 4; ++r) {
        float cr = __shfl(corr, kg * 4 + r);
#pragma unroll
        for (int df = 0; df < 4; ++df) oacc[df][r] *= cr;
      }
    }

    float ps = 0.f;
#pragma unroll
    for (int j = 0; j < 4; ++j) {
      float p0 = exp2f(sacc[j][0] - m_);
      float p1 = exp2f(sacc[j][1] - m_);
      float p2 = exp2f(sacc[j][2] - m_);
      float p3 = exp2f(sacc[j][3] - m_);
      ps += (p0 + p1) + (p2 + p3);
      bf16x4 pp = { (bf16)p0, (bf16)p1, (bf16)p2, (bf16)p3 };
      *reinterpret_cast<bf16x4*>(&lP[wave][fr * 68 + j * 16 + kg * 4]) = pp;
    }
    ps += __shfl_xor(ps, 16);
    ps += __shfl_xor(ps, 32);
    l_ += ps;

    __syncthreads();   // barrier B: VT(t), K(t+1) staged+visible; P visible

    __builtin_amdgcn_s_setprio(1);
#pragma unroll
    for (int ks = 0; ks < 2; ++ks) {
      bf16x8 pf = *reinterpret_cast<const bf16x8*>(&lP[wave][fr * 68 + ks * 32 + kg * 8]);
#pragma unroll
      for (int df = 0; df < 4; ++df) {
        int d = df * 16 + fr;
        bf16x8 vf = *reinterpret_cast<const bf16x8*>(
            (const bf16*)lVT + d * 64 + (((kg + 4 * ks) ^ (d & 7)) << 3));
        oacc[df] = __builtin_amdgcn_mfma_f32_16x16x32_bf16(pf, vf, oacc[df], 0, 0, 0);
      }
    }
    __builtin_amdgcn_s_setprio(0);

    __syncthreads();   // barrier A: lVT + lP free for next iter
  }

  float linv[4];
#pragma unroll
  for (int r = 0; r < 4; ++r) linv[r] = 1.0f / __shfl(l_, kg * 4 + r);
#pragma unroll
  for (int df = 0; df < 4; ++df)
#pragma unroll
    for (int r = 0; r < 4; ++r)
      Ob[(size_t)(qrow0 + kg * 4 + r) * NE + df * 16 + fr] = (bf16)(oacc[df][r] * linv[r]);
}

extern "C" void kernel_launch(void* const* d_in, const int* in_sizes, int n_in,
                              void* d_out, int out_size, void* d_ws, size_t ws_size,
                              hipStream_t stream) {
  const float* hs  = (const float*)d_in[0];
  const float* rot = (const float*)d_in[1];
  const float* qw  = (const float*)d_in[2];
  const float* kw  = (const float*)d_in[3];
  const float* vw  = (const float*)d_in[4];
  const float* ow  = (const float*)d_in[5];
  const float* obb = (const float*)d_in[6];
  float* out = (float*)d_out;

  char* ws = (char*)d_ws;
  size_t off = 0;
  bf16* hb  = (bf16*)(ws + off); off += (size_t)NM * NE * 2;
  bf16* wqb = (bf16*)(ws + off); off += (size_t)NE * NE * 2;
  bf16* wkb = (bf16*)(ws + off); off += (size_t)NE * NE * 2;
  bf16* wvb = (bf16*)(ws + off); off += (size_t)NE * NE * 2;
  bf16* wob = (bf16*)(ws + off); off += (size_t)NE * NE * 2;
  bf16* qb  = (bf16*)(ws + off); off += (size_t)NM * NE * 2;
  bf16* kb  = (bf16*)(ws + off); off += (size_t)NM * NE * 2;
  bf16* vt  = (bf16*)(ws + off); off += (size_t)NM * NE * 2;   // [bh][d][s]
  float* ct = (float*)(ws + off); off += (size_t)NS * NROT * 4;
  float* st = (float*)(ws + off); off += (size_t)NS * NROT * 4;
  bf16* aob = hb;   // hidden bf16 is dead after projections

  // fused prep (one dispatch): 4 weight-cvt slices, 4 hidden-cvt slices, tables
  PrepArgs pa = { qw, kw, vw, ow, wqb, wkb, wvb, wob, hs, hb, rot, ct, st };
  k_prep<<<dim3(NE * NE / 4 / 256, 9), dim3(256), 0, stream>>>(pa);

  // fused Q/K/VT projections + rope (256^2 tiles, BK=32 triple-buffered)
  k_proj<<<dim3(NM / 256, NE / 256, 3), dim3(512), 0, stream>>>(
      hb, wqb, wkb, wvb, qb, kb, vt, ct, st);

  // causal flash attention (single-tile blocks, qt-descending, 1024 blocks)
  k_attn<<<dim3(8, 128), dim3(256), 0, stream>>>(qb, kb, vt, aob);

  // output projection + bias (simple single-buffered core)
  k_gemm_o<<<dim3(NM / 64, NE / 128), dim3(256), 0, stream>>>(aob, wob, out, obb);

  (void)in_sizes; (void)n_in; (void)out_size; (void)ws_size;
}

// Round 16
// 96.737 us; speedup vs baseline: 1.0720x; 1.0720x over previous
//
#include <hip/hip_runtime.h>
#include <hip/hip_bf16.h>

typedef __bf16 bf16;
typedef __attribute__((ext_vector_type(2))) __bf16 bf16x2;
typedef __attribute__((ext_vector_type(4))) __bf16 bf16x4;
typedef __attribute__((ext_vector_type(8))) __bf16 bf16x8;
typedef __attribute__((ext_vector_type(4))) float f32x4;

#define NB 4
#define NS 1024
#define NE 1024
#define NH 16
#define ND 64
#define NROT 32
#define NM (NB*NS)   // 4096 rows

// ---- async global->LDS, 16B per lane, wave-uniform LDS base ----
__device__ __forceinline__ void gload_lds16(const bf16* g, void* l) {
  __builtin_amdgcn_global_load_lds(
      (const __attribute__((address_space(1))) unsigned int*)g,
      (__attribute__((address_space(3))) unsigned int*)l,
      16, 0, 0);
}

// ---- fused prep: weight cvt (y<4), hidden cvt (y<8), rope tables (y==8) ----
struct PrepArgs {
  const float* w0; const float* w1; const float* w2; const float* w3;
  bf16* b0; bf16* b1; bf16* b2; bf16* b3;
  const float* hs; bf16* hb;
  const float* rot; float* ct; float* st;
};
__global__ void k_prep(PrepArgs a) {
  const int y = blockIdx.y;
  const int i = blockIdx.x * 256 + threadIdx.x;
  if (y < 4) {
    const float* s = (y == 0) ? a.w0 : (y == 1) ? a.w1 : (y == 2) ? a.w2 : a.w3;
    bf16* d = (y == 0) ? a.b0 : (y == 1) ? a.b1 : (y == 2) ? a.b2 : a.b3;
    float4 v = reinterpret_cast<const float4*>(s)[i];
    bf16x4 o = { (bf16)v.x, (bf16)v.y, (bf16)v.z, (bf16)v.w };
    *reinterpret_cast<bf16x4*>(d + (size_t)i * 4) = o;
  } else if (y < 8) {
    size_t off = (size_t)(y - 4) * (NM * NE / 16);   // quarter of hidden, in float4s
    float4 v = reinterpret_cast<const float4*>(a.hs)[off + i];
    bf16x4 o = { (bf16)v.x, (bf16)v.y, (bf16)v.z, (bf16)v.w };
    *reinterpret_cast<bf16x4*>(a.hb + (off + i) * 4) = o;
  } else {
    if (i < NS * NROT) {
      float v = a.rot[i];
      a.ct[i] = cosf(v);
      a.st[i] = sinf(v);
    }
  }
}

// =====================================================================
// 256x256-tile GEMM core, fine-phase schedule (R11 — best measured proj).
// 512 threads / 8 waves (2M x 4N), wave C = 128x64. BK=64 double-buffered.
// =====================================================================
template<bool SWAP>
__device__ __forceinline__ void gemm_core256(
    const bf16* __restrict__ A, const bf16* __restrict__ W,
    bf16* lA, bf16* lB, int m0, int n0, f32x4 (&acc)[32])
{
  const int tid = threadIdx.x;
  const int wave = tid >> 6, lane = tid & 63;
  const int wm = wave >> 2, wn = wave & 3;      // 2 m-halves x 4 n-quarters
  const int fr = lane & 15, kg = lane >> 4;
  const int lrow8 = lane >> 3, lslot = lane & 7;

  // stage one half-tile h: 0=A rows0-127, 1=A rows128-255, 2=B lo, 3=B hi
  auto stageH = [&](int kt, int c, int h) {
    const bf16* src = (h < 2) ? A : W;
    bf16* dst = (h < 2) ? lA : lB;
    const int base0 = (h < 2) ? m0 : n0;
    const int hh = h & 1;
#pragma unroll
    for (int i = 0; i < 2; ++i) {
      int chunk = hh * 16 + i * 8 + wave;       // 16 chunks per half / 8 waves
      int row = (chunk << 3) + lrow8;           // 0..255
      int slot = lslot ^ (row & 7);
      gload_lds16(src + (size_t)(base0 + row) * NE + kt + slot * 8,
                  (char*)dst + c * 32768 + chunk * 1024);
    }
  };

  // prologue: K-tile 0 fully staged
#pragma unroll
  for (int h = 0; h < 4; ++h) stageH(0, 0, h);
  asm volatile("s_waitcnt vmcnt(0)\n\ts_barrier" ::: "memory");

  constexpr int NT = NE / 64;   // 16
  bf16x8 bfrag[4][2];

  for (int t = 0; t < NT; ++t) {
    const int c = t & 1;
    const char* cA = (const char*)lA + c * 32768;
    const char* cB = (const char*)lB + c * 32768;

#pragma unroll
    for (int q = 0; q < 4; ++q) {
      if (t + 1 < NT) stageH((t + 1) * 64, c ^ 1, q);

      if (q == 0) {
        if (t > 0) {
          if (t + 1 < NT)
            asm volatile("s_waitcnt vmcnt(2)\n\ts_barrier" ::: "memory");
          else
            asm volatile("s_waitcnt vmcnt(0)\n\ts_barrier" ::: "memory");
        }
#pragma unroll
        for (int j = 0; j < 4; ++j) {
          int rb = wn * 64 + j * 16 + fr;
#pragma unroll
          for (int kk = 0; kk < 2; ++kk)
            bfrag[j][kk] = *reinterpret_cast<const bf16x8*>(
                cB + rb * 128 + (((kg + 4 * kk) ^ (rb & 7)) << 4));
        }
      }

      bf16x8 af[2][2];
#pragma unroll
      for (int u = 0; u < 2; ++u) {
        int ra = wm * 128 + (2 * q + u) * 16 + fr;
#pragma unroll
        for (int kk = 0; kk < 2; ++kk)
          af[u][kk] = *reinterpret_cast<const bf16x8*>(
              cA + ra * 128 + (((kg + 4 * kk) ^ (ra & 7)) << 4));
      }

      __builtin_amdgcn_sched_barrier(0);
      __builtin_amdgcn_s_setprio(1);
#pragma unroll
      for (int kk = 0; kk < 2; ++kk)
#pragma unroll
        for (int u = 0; u < 2; ++u)
#pragma unroll
          for (int j = 0; j < 4; ++j) {
            const int i = 2 * q + u;
            if constexpr (SWAP)
              acc[j * 8 + i] = __builtin_amdgcn_mfma_f32_16x16x32_bf16(
                  bfrag[j][kk], af[u][kk], acc[j * 8 + i], 0, 0, 0);
            else
              acc[i * 4 + j] = __builtin_amdgcn_mfma_f32_16x16x32_bf16(
                  af[u][kk], bfrag[j][kk], acc[i * 4 + j], 0, 0, 0);
          }
      __builtin_amdgcn_s_setprio(0);
      __builtin_amdgcn_sched_barrier(0);
    }

    asm volatile("s_waitcnt lgkmcnt(0)\n\ts_barrier" ::: "memory");
  }
}

// ---- fused projections + rope, 256^2 tiles: z=0 Q, z=1 K, z=2 V-transposed ----
__global__ __launch_bounds__(512) void k_proj(
    const bf16* __restrict__ A, const bf16* __restrict__ Wq, const bf16* __restrict__ Wk,
    const bf16* __restrict__ Wv, bf16* __restrict__ Oq, bf16* __restrict__ Ok,
    bf16* __restrict__ vt, const float* __restrict__ ct, const float* __restrict__ st)
{
  __shared__ bf16 lA[2 * 256 * 64];
  __shared__ bf16 lB[2 * 256 * 64];
  const int z = blockIdx.z;
  const int m0 = blockIdx.x * 256, n0 = blockIdx.y * 256;
  const int tid = threadIdx.x;
  const int wave = tid >> 6, lane = tid & 63;
  const int wm = wave >> 2, wn = wave & 3;
  const int fr = lane & 15, kg = lane >> 4;

  f32x4 acc[32] = {};

  if (z == 2) {
    gemm_core256<true>(A, Wv, lA, lB, m0, n0, acc);

    const int b = m0 >> 10;
    const int h = (n0 + wn * 64) >> 6;
    bf16* vtb = vt + ((size_t)(b * 16 + h)) * ND * NS;
#pragma unroll
    for (int i = 0; i < 8; ++i) {
      int sl = (m0 & (NS - 1)) + wm * 128 + i * 16 + fr;
#pragma unroll
      for (int r = 0; r < 4; ++r) {
        int dbase = kg * 4 + r;
        float x0 = acc[0 * 8 + i][r];
        float x1 = acc[1 * 8 + i][r];
        float c0 = ct[sl * NROT + dbase],      sn0 = st[sl * NROT + dbase];
        float c1 = ct[sl * NROT + 16 + dbase], sn1 = st[sl * NROT + 16 + dbase];
        float y0 = x0 * c0 - x1 * sn0;
        float y1 = x1 * c1 + x0 * sn1;
        vtb[(size_t)(dbase)      * NS + sl] = (bf16)y0;
        vtb[(size_t)(16 + dbase) * NS + sl] = (bf16)y1;
        vtb[(size_t)(32 + dbase) * NS + sl] = (bf16)acc[2 * 8 + i][r];
        vtb[(size_t)(48 + dbase) * NS + sl] = (bf16)acc[3 * 8 + i][r];
      }
    }
  } else {
    const bf16* W = (z == 0) ? Wq : Wk;
    bf16* Og = (z == 0) ? Oq : Ok;
    const float scale = (z == 0) ? 0.125f * 1.44269504f : 1.0f;

    gemm_core256<false>(A, W, lA, lB, m0, n0, acc);

#pragma unroll
    for (int i = 0; i < 8; ++i) {
      int rowbase = m0 + wm * 128 + i * 16 + kg * 4;
#pragma unroll
      for (int r = 0; r < 4; ++r) {
        int gm = rowbase + r;
        int s = gm & (NS - 1);
        float x0 = acc[i * 4 + 0][r] * scale;
        float x1 = acc[i * 4 + 1][r] * scale;
        float c0 = ct[s * NROT + fr],      sn0 = st[s * NROT + fr];
        float c1 = ct[s * NROT + 16 + fr], sn1 = st[s * NROT + 16 + fr];
        float y0 = x0 * c0 - x1 * sn0;
        float y1 = x1 * c1 + x0 * sn1;
        size_t rb = (size_t)gm * NE + n0 + wn * 64;
        Og[rb + 0 * 16 + fr] = (bf16)y0;
        Og[rb + 1 * 16 + fr] = (bf16)y1;
        Og[rb + 2 * 16 + fr] = (bf16)(acc[i * 4 + 2][r] * scale);
        Og[rb + 3 * 16 + fr] = (bf16)(acc[i * 4 + 3][r] * scale);
      }
    }
  }
}

// ---- output projection + bias: R6 simple single-buffered core ----
__global__ __launch_bounds__(256) void k_gemm_o(
    const bf16* __restrict__ A, const bf16* __restrict__ W, float* __restrict__ Og,
    const float* __restrict__ bias)
{
  __shared__ bf16 lA[64 * 64];
  __shared__ bf16 lB[128 * 64];
  const int m0 = blockIdx.x * 64, n0 = blockIdx.y * 128;
  const int tid = threadIdx.x;
  const int wave = tid >> 6, lane = tid & 63;
  const int wm = wave >> 1, wn = wave & 1;
  const int fr = lane & 15, kg = lane >> 4;
  const int lrow8 = lane >> 3, lslot = lane & 7;

  f32x4 acc[2][4] = {};

  for (int kt = 0; kt < NE; kt += 64) {
#pragma unroll
    for (int i = 0; i < 2; ++i) {
      int chunk = i * 4 + wave;
      int row = (chunk << 3) + lrow8;
      int slot = lslot ^ (row & 7);
      gload_lds16(A + (size_t)(m0 + row) * NE + kt + slot * 8, (char*)lA + chunk * 1024);
    }
#pragma unroll
    for (int i = 0; i < 4; ++i) {
      int chunk = i * 4 + wave;
      int row = (chunk << 3) + lrow8;
      int slot = lslot ^ (row & 7);
      gload_lds16(W + (size_t)(n0 + row) * NE + kt + slot * 8, (char*)lB + chunk * 1024);
    }
    __syncthreads();
#pragma unroll
    for (int kk = 0; kk < 2; ++kk) {
      bf16x8 af[2], bfr[4];
#pragma unroll
      for (int i = 0; i < 2; ++i) {
        int ra = wm * 32 + i * 16 + fr;
        af[i] = *reinterpret_cast<const bf16x8*>(lA + ra * 64 + (((kg + 4 * kk) ^ (ra & 7)) << 3));
      }
#pragma unroll
      for (int j = 0; j < 4; ++j) {
        int rb = wn * 64 + j * 16 + fr;
        bfr[j] = *reinterpret_cast<const bf16x8*>(lB + rb * 64 + (((kg + 4 * kk) ^ (rb & 7)) << 3));
      }
#pragma unroll
      for (int i = 0; i < 2; ++i)
#pragma unroll
        for (int j = 0; j < 4; ++j)
          acc[i][j] = __builtin_amdgcn_mfma_f32_16x16x32_bf16(af[i], bfr[j], acc[i][j], 0, 0, 0);
    }
    __syncthreads();
  }

#pragma unroll
  for (int i = 0; i < 2; ++i)
#pragma unroll
    for (int j = 0; j < 4; ++j) {
      int gc = n0 + wn * 64 + j * 16 + fr;
      float bv = bias[gc];
#pragma unroll
      for (int r = 0; r < 4; ++r) {
        int gm = m0 + wm * 32 + i * 16 + kg * 4 + r;
        Og[(size_t)gm * NE + gc] = acc[i][j][r] + bv;
      }
    }
}

// ---- causal flash attention: swapped-QK^T in-lane softmax, ONE barrier/tile.
// lK AND lVT double-buffered; lP wave-private. Per tile: issue VT/K(t+1) ->
// QK(t) -> softmax -> P write -> PV(t) -> vmcnt(0)+barrier. All ds_reads of
// buf c drain before their MFMAs (pre-barrier); t+1 DMA writes only post-barrier.
__global__ __launch_bounds__(256) void k_attn(
    const bf16* __restrict__ Q, const bf16* __restrict__ K,
    const bf16* __restrict__ VT, bf16* __restrict__ O)
{
  __shared__ bf16 lK[2][64 * 64];
  __shared__ bf16 lVT[2][64 * 64];
  __shared__ bf16 lP[4][16 * 68];
  const int tid = threadIdx.x;
  const int wave = tid >> 6, lane = tid & 63;
  const int fr = lane & 15, kg = lane >> 4;

  const int qt = 15 - (blockIdx.y >> 3);          // descending: long blocks first
  const int bh = blockIdx.x | ((blockIdx.y & 7) << 3);
  const int b = bh >> 4, h = bh & 15;
  const int nt = qt + 1;
  const bf16* Qb  = Q + (size_t)b * NS * NE + h * 64;
  const bf16* Kb  = K + (size_t)b * NS * NE + h * 64;
  const bf16* VTb = VT + (size_t)bh * ND * NS;
  bf16* Ob = O + (size_t)b * NS * NE + h * 64;

  const int qrow0 = qt * 64 + wave * 16;

  bf16x8 qf[2];
#pragma unroll
  for (int kk = 0; kk < 2; ++kk)
    qf[kk] = *reinterpret_cast<const bf16x8*>(
        Qb + (size_t)(qrow0 + fr) * NE + kk * 32 + kg * 8);

  const int srow = lane >> 3;
  const int sslot = (lane & 7) ^ srow;
  const int r0 = wave * 8 + srow;
  const int r1 = (wave + 4) * 8 + srow;
  const bf16* kA0 = Kb + (size_t)r0 * NE + sslot * 8;
  const bf16* kA1 = Kb + (size_t)r1 * NE + sslot * 8;
  const bf16* vA0 = VTb + (size_t)r0 * NS + sslot * 8;
  const bf16* vA1 = VTb + (size_t)r1 * NS + sslot * 8;
  char* ldsKa[2] = { (char*)lK[0] + wave * 1024, (char*)lK[1] + wave * 1024 };
  char* ldsKb[2] = { (char*)lK[0] + (wave + 4) * 1024, (char*)lK[1] + (wave + 4) * 1024 };
  char* ldsVa[2] = { (char*)lVT[0] + wave * 1024, (char*)lVT[1] + wave * 1024 };
  char* ldsVb[2] = { (char*)lVT[0] + (wave + 4) * 1024, (char*)lVT[1] + (wave + 4) * 1024 };

  float m_ = -3.0e38f, l_ = 0.f;
  f32x4 oacc[4] = {};

  // prologue: K(0), VT(0) -> buf 0
  gload_lds16(kA0, ldsKa[0]);
  gload_lds16(kA1, ldsKb[0]);
  gload_lds16(vA0, ldsVa[0]);
  gload_lds16(vA1, ldsVb[0]);
  __syncthreads();

  for (int t = 0; t < nt; ++t) {
    const int c = t & 1;
    // issue next tile's K and VT into the other buffer (free post-barrier)
    if (t + 1 < nt) {
      gload_lds16(kA0 + (size_t)(t + 1) * 64 * NE, ldsKa[c ^ 1]);
      gload_lds16(kA1 + (size_t)(t + 1) * 64 * NE, ldsKb[c ^ 1]);
      gload_lds16(vA0 + (t + 1) * 64, ldsVa[c ^ 1]);
      gload_lds16(vA1 + (t + 1) * 64, ldsVb[c ^ 1]);
    }

    // QK^T swapped: sacc[j][r] = S[kv = 16j+4kg+r][q = qrow0+fr]
    const bf16* lKc = lK[c];
    f32x4 sacc[4] = {};
    __builtin_amdgcn_s_setprio(1);
#pragma unroll
    for (int kk = 0; kk < 2; ++kk)
#pragma unroll
      for (int j = 0; j < 4; ++j) {
        int rc = j * 16 + fr;
        bf16x8 kf = *reinterpret_cast<const bf16x8*>(
            lKc + rc * 64 + (((kg + 4 * kk) ^ (rc & 7)) << 3));
        sacc[j] = __builtin_amdgcn_mfma_f32_16x16x32_bf16(kf, qf[kk], sacc[j], 0, 0, 0);
      }
    __builtin_amdgcn_s_setprio(0);

    if (t == qt) {
      const int ql = wave * 16 + fr;
#pragma unroll
      for (int j = 0; j < 4; ++j)
#pragma unroll
        for (int r = 0; r < 4; ++r)
          if (16 * j + 4 * kg + r > ql) sacc[j][r] = -3.0e38f;
    }

    float m4 = fmaxf(fmaxf(fmaxf(sacc[0][0], sacc[0][1]), fmaxf(sacc[0][2], sacc[0][3])),
                     fmaxf(fmaxf(sacc[1][0], sacc[1][1]), fmaxf(sacc[1][2], sacc[1][3])));
    m4 = fmaxf(m4, fmaxf(fmaxf(fmaxf(sacc[2][0], sacc[2][1]), fmaxf(sacc[2][2], sacc[2][3])),
                         fmaxf(fmaxf(sacc[3][0], sacc[3][1]), fmaxf(sacc[3][2], sacc[3][3]))));
    m4 = fmaxf(m4, __shfl_xor(m4, 16));
    m4 = fmaxf(m4, __shfl_xor(m4, 32));

    if (!__all(m4 - m_ <= 8.0f)) {
      float nm = fmaxf(m_, m4);
      float corr = exp2f(m_ - nm);
      m_ = nm;
      l_ *= corr;
#pragma unroll
      for (int r = 0; r < 4; ++r) {
        float cr = __shfl(corr, kg * 4 + r);
#pragma unroll
        for (int df = 0; df < 4; ++df) oacc[df][r] *= cr;
      }
    }

    float ps = 0.f;
#pragma unroll
    for (int j = 0; j < 4; ++j) {
      float p0 = exp2f(sacc[j][0] - m_);
      float p1 = exp2f(sacc[j][1] - m_);
      float p2 = exp2f(sacc[j][2] - m_);
      float p3 = exp2f(sacc[j][3] - m_);
      ps += (p0 + p1) + (p2 + p3);
      bf16x4 pp = { (bf16)p0, (bf16)p1, (bf16)p2, (bf16)p3 };
      *reinterpret_cast<bf16x4*>(&lP[wave][fr * 68 + j * 16 + kg * 4]) = pp;
    }
    ps += __shfl_xor(ps, 16);
    ps += __shfl_xor(ps, 32);
    l_ += ps;

    // PV from lVT[c]; lP wave-private (same-wave lgkm ordering suffices)
    const bf16* lVc = lVT[c];
    __builtin_amdgcn_s_setprio(1);
#pragma unroll
    for (int ks = 0; ks < 2; ++ks) {
      bf16x8 pf = *reinterpret_cast<const bf16x8*>(&lP[wave][fr * 68 + ks * 32 + kg * 8]);
#pragma unroll
      for (int df = 0; df < 4; ++df) {
        int d = df * 16 + fr;
        bf16x8 vf = *reinterpret_cast<const bf16x8*>(
            lVc + d * 64 + (((kg + 4 * ks) ^ (d & 7)) << 3));
        oacc[df] = __builtin_amdgcn_mfma_f32_16x16x32_bf16(pf, vf, oacc[df], 0, 0, 0);
      }
    }
    __builtin_amdgcn_s_setprio(0);

    // single barrier: K/VT(t+1) drained (covered by whole tile compute);
    // all waves' buf-c reads retired pre-MFMA -> buf c free next iteration
    if (t + 1 < nt)
      asm volatile("s_waitcnt vmcnt(0)\n\ts_barrier" ::: "memory");
  }

  float linv[4];
#pragma unroll
  for (int r = 0; r < 4; ++r) linv[r] = 1.0f / __shfl(l_, kg * 4 + r);
#pragma unroll
  for (int df = 0; df < 4; ++df)
#pragma unroll
    for (int r = 0; r < 4; ++r)
      Ob[(size_t)(qrow0 + kg * 4 + r) * NE + df * 16 + fr] = (bf16)(oacc[df][r] * linv[r]);
}

extern "C" void kernel_launch(void* const* d_in, const int* in_sizes, int n_in,
                              void* d_out, int out_size, void* d_ws, size_t ws_size,
                              hipStream_t stream) {
  const float* hs  = (const float*)d_in[0];
  const float* rot = (const float*)d_in[1];
  const float* qw  = (const float*)d_in[2];
  const float* kw  = (const float*)d_in[3];
  const float* vw  = (const float*)d_in[4];
  const float* ow  = (const float*)d_in[5];
  const float* obb = (const float*)d_in[6];
  float* out = (float*)d_out;

  char* ws = (char*)d_ws;
  size_t off = 0;
  bf16* hb  = (bf16*)(ws + off); off += (size_t)NM * NE * 2;
  bf16* wqb = (bf16*)(ws + off); off += (size_t)NE * NE * 2;
  bf16* wkb = (bf16*)(ws + off); off += (size_t)NE * NE * 2;
  bf16* wvb = (bf16*)(ws + off); off += (size_t)NE * NE * 2;
  bf16* wob = (bf16*)(ws + off); off += (size_t)NE * NE * 2;
  bf16* qb  = (bf16*)(ws + off); off += (size_t)NM * NE * 2;
  bf16* kb  = (bf16*)(ws + off); off += (size_t)NM * NE * 2;
  bf16* vt  = (bf16*)(ws + off); off += (size_t)NM * NE * 2;   // [bh][d][s]
  float* ct = (float*)(ws + off); off += (size_t)NS * NROT * 4;
  float* st = (float*)(ws + off); off += (size_t)NS * NROT * 4;
  bf16* aob = hb;   // hidden bf16 is dead after projections

  // fused prep (one dispatch): 4 weight-cvt slices, 4 hidden-cvt slices, tables
  PrepArgs pa = { qw, kw, vw, ow, wqb, wkb, wvb, wob, hs, hb, rot, ct, st };
  k_prep<<<dim3(NE * NE / 4 / 256, 9), dim3(256), 0, stream>>>(pa);

  // fused Q/K/VT projections + rope (256^2 tiles, fine-phase schedule)
  k_proj<<<dim3(NM / 256, NE / 256, 3), dim3(512), 0, stream>>>(
      hb, wqb, wkb, wvb, qb, kb, vt, ct, st);

  // causal flash attention (single-tile blocks, qt-descending, 1024 blocks)
  k_attn<<<dim3(8, 128), dim3(256), 0, stream>>>(qb, kb, vt, aob);

  // output projection + bias (simple single-buffered core)
  k_gemm_o<<<dim3(NM / 64, NE / 128), dim3(256), 0, stream>>>(aob, wob, out, obb);

  (void)in_sizes; (void)n_in; (void)out_size; (void)ws_size;
}

// Round 17
// 95.444 us; speedup vs baseline: 1.0865x; 1.0135x over previous
//
#include <hip/hip_runtime.h>
#include <hip/hip_bf16.h>

typedef __bf16 bf16;
typedef __attribute__((ext_vector_type(2))) __bf16 bf16x2;
typedef __attribute__((ext_vector_type(4))) __bf16 bf16x4;
typedef __attribute__((ext_vector_type(8))) __bf16 bf16x8;
typedef __attribute__((ext_vector_type(4))) float f32x4;

#define NB 4
#define NS 1024
#define NE 1024
#define NH 16
#define ND 64
#define NROT 32
#define NM (NB*NS)   // 4096 rows

// ---- async global->LDS, 16B per lane, wave-uniform LDS base ----
__device__ __forceinline__ void gload_lds16(const bf16* g, void* l) {
  __builtin_amdgcn_global_load_lds(
      (const __attribute__((address_space(1))) unsigned int*)g,
      (__attribute__((address_space(3))) unsigned int*)l,
      16, 0, 0);
}

// ---- fused prep: weight cvt (y<4), hidden cvt (y<8), rope tables (y==8) ----
struct PrepArgs {
  const float* w0; const float* w1; const float* w2; const float* w3;
  bf16* b0; bf16* b1; bf16* b2; bf16* b3;
  const float* hs; bf16* hb;
  const float* rot; float* ct; float* st;
};
__global__ void k_prep(PrepArgs a) {
  const int y = blockIdx.y;
  const int i = blockIdx.x * 256 + threadIdx.x;
  if (y < 4) {
    const float* s = (y == 0) ? a.w0 : (y == 1) ? a.w1 : (y == 2) ? a.w2 : a.w3;
    bf16* d = (y == 0) ? a.b0 : (y == 1) ? a.b1 : (y == 2) ? a.b2 : a.b3;
    float4 v = reinterpret_cast<const float4*>(s)[i];
    bf16x4 o = { (bf16)v.x, (bf16)v.y, (bf16)v.z, (bf16)v.w };
    *reinterpret_cast<bf16x4*>(d + (size_t)i * 4) = o;
  } else if (y < 8) {
    size_t off = (size_t)(y - 4) * (NM * NE / 16);   // quarter of hidden, in float4s
    float4 v = reinterpret_cast<const float4*>(a.hs)[off + i];
    bf16x4 o = { (bf16)v.x, (bf16)v.y, (bf16)v.z, (bf16)v.w };
    *reinterpret_cast<bf16x4*>(a.hb + (off + i) * 4) = o;
  } else {
    if (i < NS * NROT) {
      float v = a.rot[i];
      a.ct[i] = cosf(v);
      a.st[i] = sinf(v);
    }
  }
}

// =====================================================================
// 256x256-tile GEMM core, fine-phase schedule + deeper counted flight.
// 512 threads / 8 waves (2M x 4N), wave C = 128x64. BK=64 double-buffered.
// Stage schedule: q0 issues h0+h1 of tile t+1 BEFORE the publish barrier
// (vmcnt(4): 4 loads fly across it), q1 -> h2, q2 -> h3, q3 -> none.
// h0/h1 target buf c^1 whose readers retired at t-1's end-of-tile
// lgkmcnt(0)+barrier -> race-free.
// =====================================================================
template<bool SWAP>
__device__ __forceinline__ void gemm_core256(
    const bf16* __restrict__ A, const bf16* __restrict__ W,
    bf16* lA, bf16* lB, int m0, int n0, f32x4 (&acc)[32])
{
  const int tid = threadIdx.x;
  const int wave = tid >> 6, lane = tid & 63;
  const int wm = wave >> 2, wn = wave & 3;      // 2 m-halves x 4 n-quarters
  const int fr = lane & 15, kg = lane >> 4;
  const int lrow8 = lane >> 3, lslot = lane & 7;

  // stage one half-tile h: 0=A rows0-127, 1=A rows128-255, 2=B lo, 3=B hi
  auto stageH = [&](int kt, int c, int h) {
    const bf16* src = (h < 2) ? A : W;
    bf16* dst = (h < 2) ? lA : lB;
    const int base0 = (h < 2) ? m0 : n0;
    const int hh = h & 1;
#pragma unroll
    for (int i = 0; i < 2; ++i) {
      int chunk = hh * 16 + i * 8 + wave;       // 16 chunks per half / 8 waves
      int row = (chunk << 3) + lrow8;           // 0..255
      int slot = lslot ^ (row & 7);
      gload_lds16(src + (size_t)(base0 + row) * NE + kt + slot * 8,
                  (char*)dst + c * 32768 + chunk * 1024);
    }
  };

  // prologue: K-tile 0 fully staged
#pragma unroll
  for (int h = 0; h < 4; ++h) stageH(0, 0, h);
  asm volatile("s_waitcnt vmcnt(0)\n\ts_barrier" ::: "memory");

  constexpr int NT = NE / 64;   // 16
  bf16x8 bfrag[4][2];

  for (int t = 0; t < NT; ++t) {
    const int c = t & 1;
    const char* cA = (const char*)lA + c * 32768;
    const char* cB = (const char*)lB + c * 32768;

#pragma unroll
    for (int q = 0; q < 4; ++q) {
      // stage schedule: q0 -> h0+h1 (pre-barrier), q1 -> h2, q2 -> h3
      if (t + 1 < NT) {
        if (q == 0) { stageH((t + 1) * 64, c ^ 1, 0); stageH((t + 1) * 64, c ^ 1, 1); }
        else if (q < 3) stageH((t + 1) * 64, c ^ 1, q + 1);
      }

      if (q == 0) {
        // publish K-tile t: wait own 8 stage-loads of tile t; the 4
        // just-issued (t+1 h0,h1) stay in flight.
        if (t > 0) {
          if (t + 1 < NT)
            asm volatile("s_waitcnt vmcnt(4)\n\ts_barrier" ::: "memory");
          else
            asm volatile("s_waitcnt vmcnt(0)\n\ts_barrier" ::: "memory");
        }
        // hoist B fragments for the whole K-tile (8 reads)
#pragma unroll
        for (int j = 0; j < 4; ++j) {
          int rb = wn * 64 + j * 16 + fr;
#pragma unroll
          for (int kk = 0; kk < 2; ++kk)
            bfrag[j][kk] = *reinterpret_cast<const bf16x8*>(
                cB + rb * 128 + (((kg + 4 * kk) ^ (rb & 7)) << 4));
        }
      }

      // A fragments for this quadrant (4 reads)
      bf16x8 af[2][2];
#pragma unroll
      for (int u = 0; u < 2; ++u) {
        int ra = wm * 128 + (2 * q + u) * 16 + fr;
#pragma unroll
        for (int kk = 0; kk < 2; ++kk)
          af[u][kk] = *reinterpret_cast<const bf16x8*>(
              cA + ra * 128 + (((kg + 4 * kk) ^ (ra & 7)) << 4));
      }

      __builtin_amdgcn_sched_barrier(0);
      __builtin_amdgcn_s_setprio(1);
#pragma unroll
      for (int kk = 0; kk < 2; ++kk)
#pragma unroll
        for (int u = 0; u < 2; ++u)
#pragma unroll
          for (int j = 0; j < 4; ++j) {
            const int i = 2 * q + u;
            if constexpr (SWAP)
              acc[j * 8 + i] = __builtin_amdgcn_mfma_f32_16x16x32_bf16(
                  bfrag[j][kk], af[u][kk], acc[j * 8 + i], 0, 0, 0);
            else
              acc[i * 4 + j] = __builtin_amdgcn_mfma_f32_16x16x32_bf16(
                  af[u][kk], bfrag[j][kk], acc[i * 4 + j], 0, 0, 0);
          }
      __builtin_amdgcn_s_setprio(0);
      __builtin_amdgcn_sched_barrier(0);
    }

    // end of K-tile: retire all reads of buf c before t+2 overwrites it
    asm volatile("s_waitcnt lgkmcnt(0)\n\ts_barrier" ::: "memory");
  }
}

// ---- fused projections + rope, 256^2 tiles: z=0 Q, z=1 K, z=2 V-transposed ----
__global__ __launch_bounds__(512) void k_proj(
    const bf16* __restrict__ A, const bf16* __restrict__ Wq, const bf16* __restrict__ Wk,
    const bf16* __restrict__ Wv, bf16* __restrict__ Oq, bf16* __restrict__ Ok,
    bf16* __restrict__ vt, const float* __restrict__ ct, const float* __restrict__ st)
{
  __shared__ bf16 lA[2 * 256 * 64];
  __shared__ bf16 lB[2 * 256 * 64];
  const int z = blockIdx.z;
  const int m0 = blockIdx.x * 256, n0 = blockIdx.y * 256;
  const int tid = threadIdx.x;
  const int wave = tid >> 6, lane = tid & 63;
  const int wm = wave >> 2, wn = wave & 3;
  const int fr = lane & 15, kg = lane >> 4;

  f32x4 acc[32] = {};

  if (z == 2) {
    gemm_core256<true>(A, Wv, lA, lB, m0, n0, acc);

    const int b = m0 >> 10;
    const int h = (n0 + wn * 64) >> 6;
    bf16* vtb = vt + ((size_t)(b * 16 + h)) * ND * NS;
#pragma unroll
    for (int i = 0; i < 8; ++i) {
      int sl = (m0 & (NS - 1)) + wm * 128 + i * 16 + fr;
#pragma unroll
      for (int r = 0; r < 4; ++r) {
        int dbase = kg * 4 + r;
        float x0 = acc[0 * 8 + i][r];
        float x1 = acc[1 * 8 + i][r];
        float c0 = ct[sl * NROT + dbase],      sn0 = st[sl * NROT + dbase];
        float c1 = ct[sl * NROT + 16 + dbase], sn1 = st[sl * NROT + 16 + dbase];
        float y0 = x0 * c0 - x1 * sn0;
        float y1 = x1 * c1 + x0 * sn1;
        vtb[(size_t)(dbase)      * NS + sl] = (bf16)y0;
        vtb[(size_t)(16 + dbase) * NS + sl] = (bf16)y1;
        vtb[(size_t)(32 + dbase) * NS + sl] = (bf16)acc[2 * 8 + i][r];
        vtb[(size_t)(48 + dbase) * NS + sl] = (bf16)acc[3 * 8 + i][r];
      }
    }
  } else {
    const bf16* W = (z == 0) ? Wq : Wk;
    bf16* Og = (z == 0) ? Oq : Ok;
    const float scale = (z == 0) ? 0.125f * 1.44269504f : 1.0f;

    gemm_core256<false>(A, W, lA, lB, m0, n0, acc);

#pragma unroll
    for (int i = 0; i < 8; ++i) {
      int rowbase = m0 + wm * 128 + i * 16 + kg * 4;
#pragma unroll
      for (int r = 0; r < 4; ++r) {
        int gm = rowbase + r;
        int s = gm & (NS - 1);
        float x0 = acc[i * 4 + 0][r] * scale;
        float x1 = acc[i * 4 + 1][r] * scale;
        float c0 = ct[s * NROT + fr],      sn0 = st[s * NROT + fr];
        float c1 = ct[s * NROT + 16 + fr], sn1 = st[s * NROT + 16 + fr];
        float y0 = x0 * c0 - x1 * sn0;
        float y1 = x1 * c1 + x0 * sn1;
        size_t rb = (size_t)gm * NE + n0 + wn * 64;
        Og[rb + 0 * 16 + fr] = (bf16)y0;
        Og[rb + 1 * 16 + fr] = (bf16)y1;
        Og[rb + 2 * 16 + fr] = (bf16)(acc[i * 4 + 2][r] * scale);
        Og[rb + 3 * 16 + fr] = (bf16)(acc[i * 4 + 3][r] * scale);
      }
    }
  }
}

// ---- output projection + bias: simple single-buffered core (best-total cfg) ----
__global__ __launch_bounds__(256) void k_gemm_o(
    const bf16* __restrict__ A, const bf16* __restrict__ W, float* __restrict__ Og,
    const float* __restrict__ bias)
{
  __shared__ bf16 lA[64 * 64];
  __shared__ bf16 lB[128 * 64];
  const int m0 = blockIdx.x * 64, n0 = blockIdx.y * 128;
  const int tid = threadIdx.x;
  const int wave = tid >> 6, lane = tid & 63;
  const int wm = wave >> 1, wn = wave & 1;
  const int fr = lane & 15, kg = lane >> 4;
  const int lrow8 = lane >> 3, lslot = lane & 7;

  f32x4 acc[2][4] = {};

  for (int kt = 0; kt < NE; kt += 64) {
#pragma unroll
    for (int i = 0; i < 2; ++i) {
      int chunk = i * 4 + wave;
      int row = (chunk << 3) + lrow8;
      int slot = lslot ^ (row & 7);
      gload_lds16(A + (size_t)(m0 + row) * NE + kt + slot * 8, (char*)lA + chunk * 1024);
    }
#pragma unroll
    for (int i = 0; i < 4; ++i) {
      int chunk = i * 4 + wave;
      int row = (chunk << 3) + lrow8;
      int slot = lslot ^ (row & 7);
      gload_lds16(W + (size_t)(n0 + row) * NE + kt + slot * 8, (char*)lB + chunk * 1024);
    }
    __syncthreads();
#pragma unroll
    for (int kk = 0; kk < 2; ++kk) {
      bf16x8 af[2], bfr[4];
#pragma unroll
      for (int i = 0; i < 2; ++i) {
        int ra = wm * 32 + i * 16 + fr;
        af[i] = *reinterpret_cast<const bf16x8*>(lA + ra * 64 + (((kg + 4 * kk) ^ (ra & 7)) << 3));
      }
#pragma unroll
      for (int j = 0; j < 4; ++j) {
        int rb = wn * 64 + j * 16 + fr;
        bfr[j] = *reinterpret_cast<const bf16x8*>(lB + rb * 64 + (((kg + 4 * kk) ^ (rb & 7)) << 3));
      }
#pragma unroll
      for (int i = 0; i < 2; ++i)
#pragma unroll
        for (int j = 0; j < 4; ++j)
          acc[i][j] = __builtin_amdgcn_mfma_f32_16x16x32_bf16(af[i], bfr[j], acc[i][j], 0, 0, 0);
    }
    __syncthreads();
  }

#pragma unroll
  for (int i = 0; i < 2; ++i)
#pragma unroll
    for (int j = 0; j < 4; ++j) {
      int gc = n0 + wn * 64 + j * 16 + fr;
      float bv = bias[gc];
#pragma unroll
      for (int r = 0; r < 4; ++r) {
        int gm = m0 + wm * 32 + i * 16 + kg * 4 + r;
        Og[(size_t)gm * NE + gc] = acc[i][j][r] + bv;
      }
    }
}

// ---- causal flash attention: swapped-QK^T in-lane softmax, ONE barrier/tile ----
__global__ __launch_bounds__(256) void k_attn(
    const bf16* __restrict__ Q, const bf16* __restrict__ K,
    const bf16* __restrict__ VT, bf16* __restrict__ O)
{
  __shared__ bf16 lK[2][64 * 64];
  __shared__ bf16 lVT[2][64 * 64];
  __shared__ bf16 lP[4][16 * 68];
  const int tid = threadIdx.x;
  const int wave = tid >> 6, lane = tid & 63;
  const int fr = lane & 15, kg = lane >> 4;

  const int qt = 15 - (blockIdx.y >> 3);          // descending: long blocks first
  const int bh = blockIdx.x | ((blockIdx.y & 7) << 3);
  const int b = bh >> 4, h = bh & 15;
  const int nt = qt + 1;
  const bf16* Qb  = Q + (size_t)b * NS * NE + h * 64;
  const bf16* Kb  = K + (size_t)b * NS * NE + h * 64;
  const bf16* VTb = VT + (size_t)bh * ND * NS;
  bf16* Ob = O + (size_t)b * NS * NE + h * 64;

  const int qrow0 = qt * 64 + wave * 16;

  bf16x8 qf[2];
#pragma unroll
  for (int kk = 0; kk < 2; ++kk)
    qf[kk] = *reinterpret_cast<const bf16x8*>(
        Qb + (size_t)(qrow0 + fr) * NE + kk * 32 + kg * 8);

  const int srow = lane >> 3;
  const int sslot = (lane & 7) ^ srow;
  const int r0 = wave * 8 + srow;
  const int r1 = (wave + 4) * 8 + srow;
  const bf16* kA0 = Kb + (size_t)r0 * NE + sslot * 8;
  const bf16* kA1 = Kb + (size_t)r1 * NE + sslot * 8;
  const bf16* vA0 = VTb + (size_t)r0 * NS + sslot * 8;
  const bf16* vA1 = VTb + (size_t)r1 * NS + sslot * 8;
  char* ldsKa[2] = { (char*)lK[0] + wave * 1024, (char*)lK[1] + wave * 1024 };
  char* ldsKb[2] = { (char*)lK[0] + (wave + 4) * 1024, (char*)lK[1] + (wave + 4) * 1024 };
  char* ldsVa[2] = { (char*)lVT[0] + wave * 1024, (char*)lVT[1] + wave * 1024 };
  char* ldsVb[2] = { (char*)lVT[0] + (wave + 4) * 1024, (char*)lVT[1] + (wave + 4) * 1024 };

  float m_ = -3.0e38f, l_ = 0.f;
  f32x4 oacc[4] = {};

  gload_lds16(kA0, ldsKa[0]);
  gload_lds16(kA1, ldsKb[0]);
  gload_lds16(vA0, ldsVa[0]);
  gload_lds16(vA1, ldsVb[0]);
  __syncthreads();

  for (int t = 0; t < nt; ++t) {
    const int c = t & 1;
    if (t + 1 < nt) {
      gload_lds16(kA0 + (size_t)(t + 1) * 64 * NE, ldsKa[c ^ 1]);
      gload_lds16(kA1 + (size_t)(t + 1) * 64 * NE, ldsKb[c ^ 1]);
      gload_lds16(vA0 + (t + 1) * 64, ldsVa[c ^ 1]);
      gload_lds16(vA1 + (t + 1) * 64, ldsVb[c ^ 1]);
    }

    const bf16* lKc = lK[c];
    f32x4 sacc[4] = {};
    __builtin_amdgcn_s_setprio(1);
#pragma unroll
    for (int kk = 0; kk < 2; ++kk)
#pragma unroll
      for (int j = 0; j < 4; ++j) {
        int rc = j * 16 + fr;
        bf16x8 kf = *reinterpret_cast<const bf16x8*>(
            lKc + rc * 64 + (((kg + 4 * kk) ^ (rc & 7)) << 3));
        sacc[j] = __builtin_amdgcn_mfma_f32_16x16x32_bf16(kf, qf[kk], sacc[j], 0, 0, 0);
      }
    __builtin_amdgcn_s_setprio(0);

    if (t == qt) {
      const int ql = wave * 16 + fr;
#pragma unroll
      for (int j = 0; j < 4; ++j)
#pragma unroll
        for (int r = 0; r < 4; ++r)
          if (16 * j + 4 * kg + r > ql) sacc[j][r] = -3.0e38f;
    }

    float m4 = fmaxf(fmaxf(fmaxf(sacc[0][0], sacc[0][1]), fmaxf(sacc[0][2], sacc[0][3])),
                     fmaxf(fmaxf(sacc[1][0], sacc[1][1]), fmaxf(sacc[1][2], sacc[1][3])));
    m4 = fmaxf(m4, fmaxf(fmaxf(fmaxf(sacc[2][0], sacc[2][1]), fmaxf(sacc[2][2], sacc[2][3])),
                         fmaxf(fmaxf(sacc[3][0], sacc[3][1]), fmaxf(sacc[3][2], sacc[3][3]))));
    m4 = fmaxf(m4, __shfl_xor(m4, 16));
    m4 = fmaxf(m4, __shfl_xor(m4, 32));

    if (!__all(m4 - m_ <= 8.0f)) {
      float nm = fmaxf(m_, m4);
      float corr = exp2f(m_ - nm);
      m_ = nm;
      l_ *= corr;
#pragma unroll
      for (int r = 0; r < 4; ++r) {
        float cr = __shfl(corr, kg * 4 + r);
#pragma unroll
        for (int df = 0; df < 4; ++df) oacc[df][r] *= cr;
      }
    }

    float ps = 0.f;
#pragma unroll
    for (int j = 0; j < 4; ++j) {
      float p0 = exp2f(sacc[j][0] - m_);
      float p1 = exp2f(sacc[j][1] - m_);
      float p2 = exp2f(sacc[j][2] - m_);
      float p3 = exp2f(sacc[j][3] - m_);
      ps += (p0 + p1) + (p2 + p3);
      bf16x4 pp = { (bf16)p0, (bf16)p1, (bf16)p2, (bf16)p3 };
      *reinterpret_cast<bf16x4*>(&lP[wave][fr * 68 + j * 16 + kg * 4]) = pp;
    }
    ps += __shfl_xor(ps, 16);
    ps += __shfl_xor(ps, 32);
    l_ += ps;

    const bf16* lVc = lVT[c];
    __builtin_amdgcn_s_setprio(1);
#pragma unroll
    for (int ks = 0; ks < 2; ++ks) {
      bf16x8 pf = *reinterpret_cast<const bf16x8*>(&lP[wave][fr * 68 + ks * 32 + kg * 8]);
#pragma unroll
      for (int df = 0; df < 4; ++df) {
        int d = df * 16 + fr;
        bf16x8 vf = *reinterpret_cast<const bf16x8*>(
            lVc + d * 64 + (((kg + 4 * ks) ^ (d & 7)) << 3));
        oacc[df] = __builtin_amdgcn_mfma_f32_16x16x32_bf16(pf, vf, oacc[df], 0, 0, 0);
      }
    }
    __builtin_amdgcn_s_setprio(0);

    if (t + 1 < nt)
      asm volatile("s_waitcnt vmcnt(0)\n\ts_barrier" ::: "memory");
  }

  float linv[4];
#pragma unroll
  for (int r = 0; r < 4; ++r) linv[r] = 1.0f / __shfl(l_, kg * 4 + r);
#pragma unroll
  for (int df = 0; df < 4; ++df)
#pragma unroll
    for (int r = 0; r < 4; ++r)
      Ob[(size_t)(qrow0 + kg * 4 + r) * NE + df * 16 + fr] = (bf16)(oacc[df][r] * linv[r]);
}

extern "C" void kernel_launch(void* const* d_in, const int* in_sizes, int n_in,
                              void* d_out, int out_size, void* d_ws, size_t ws_size,
                              hipStream_t stream) {
  const float* hs  = (const float*)d_in[0];
  const float* rot = (const float*)d_in[1];
  const float* qw  = (const float*)d_in[2];
  const float* kw  = (const float*)d_in[3];
  const float* vw  = (const float*)d_in[4];
  const float* ow  = (const float*)d_in[5];
  const float* obb = (const float*)d_in[6];
  float* out = (float*)d_out;

  char* ws = (char*)d_ws;
  size_t off = 0;
  bf16* hb  = (bf16*)(ws + off); off += (size_t)NM * NE * 2;
  bf16* wqb = (bf16*)(ws + off); off += (size_t)NE * NE * 2;
  bf16* wkb = (bf16*)(ws + off); off += (size_t)NE * NE * 2;
  bf16* wvb = (bf16*)(ws + off); off += (size_t)NE * NE * 2;
  bf16* wob = (bf16*)(ws + off); off += (size_t)NE * NE * 2;
  bf16* qb  = (bf16*)(ws + off); off += (size_t)NM * NE * 2;
  bf16* kb  = (bf16*)(ws + off); off += (size_t)NM * NE * 2;
  bf16* vt  = (bf16*)(ws + off); off += (size_t)NM * NE * 2;   // [bh][d][s]
  float* ct = (float*)(ws + off); off += (size_t)NS * NROT * 4;
  float* st = (float*)(ws + off); off += (size_t)NS * NROT * 4;
  bf16* aob = hb;   // hidden bf16 is dead after projections

  // fused prep (one dispatch): 4 weight-cvt slices, 4 hidden-cvt slices, tables
  PrepArgs pa = { qw, kw, vw, ow, wqb, wkb, wvb, wob, hs, hb, rot, ct, st };
  k_prep<<<dim3(NE * NE / 4 / 256, 9), dim3(256), 0, stream>>>(pa);

  // fused Q/K/VT projections + rope (256^2 tiles, fine-phase, vmcnt(4) flight)
  k_proj<<<dim3(NM / 256, NE / 256, 3), dim3(512), 0, stream>>>(
      hb, wqb, wkb, wvb, qb, kb, vt, ct, st);

  // causal flash attention (single-tile blocks, qt-descending, 1024 blocks)
  k_attn<<<dim3(8, 128), dim3(256), 0, stream>>>(qb, kb, vt, aob);

  // output projection + bias (simple single-buffered core)
  k_gemm_o<<<dim3(NM / 64, NE / 128), dim3(256), 0, stream>>>(aob, wob, out, obb);

  (void)in_sizes; (void)n_in; (void)out_size; (void)ws_size;
}